// Round 9
// baseline (77.093 us; speedup 1.0000x reference)
//
#include <hip/hip_runtime.h>
#include <hip/hip_bf16.h>

#define Bn 8
#define Cn 128
#define Hn 64
#define Wn 64
#define HWn 4096
#define KK 9

typedef short short8 __attribute__((ext_vector_type(8)));
typedef float f32x4 __attribute__((ext_vector_type(4)));

// swizzle: reads 2-way (free), writes 4-way
#define SWZ(px) ((((px) >> 1) & 7) << 3)

__device__ inline unsigned short f2b(float v) {
    __hip_bfloat16 h = __float2bfloat16(v);
    return *reinterpret_cast<unsigned short*>(&h);
}
__device__ inline float b2f(unsigned short u) {
    return __uint_as_float(((unsigned int)u) << 16);
}

// ---------------------------------------------------------------------------
// K1: per-(b,c) plane. Stage X2 plane in LDS, vectorized static conv ->
// F[b][c][px] bf16 (c<128 half). Exact f32 means of Xs and Y2 -> pws.
// ---------------------------------------------------------------------------
__global__ __launch_bounds__(256) void k_pre(
    const float* __restrict__ X2, const float* __restrict__ Y2,
    const float* __restrict__ sw, unsigned short* __restrict__ F,
    float* __restrict__ pws)
{
    __shared__ float sP[HWn];
    __shared__ float red[4][2];
    int bc = blockIdx.x, b = bc >> 7, c = bc & 127, t = threadIdx.x;
    const float4* xp = (const float4*)(X2 + (size_t)bc * HWn);
    const float4* yp = (const float4*)(Y2 + (size_t)bc * HWn);

    float sy = 0.f;
#pragma unroll
    for (int i = 0; i < 4; i++) {
        int q = t + i * 256;
        float4 x = xp[q];
        ((float4*)sP)[q] = x;
        float4 y = yp[q];
        sy += y.x + y.y + y.z + y.w;
    }
    __syncthreads();

    float wk[9];
#pragma unroll
    for (int i = 0; i < 9; i++) wk[i] = sw[c * 9 + i];

    unsigned short* Fx = F + (size_t)(b * 256 + c) * HWn;
    float sx = 0.f;
#pragma unroll
    for (int g = 0; g < 4; g++) {
        int grp = t + g * 256;
        int h = grp >> 4, w4 = (grp & 15) * 4;
        float o0 = 0.f, o1 = 0.f, o2 = 0.f, o3 = 0.f;
#pragma unroll
        for (int dh = -1; dh <= 1; dh++) {
            int hh = h + dh;
            if (hh < 0 || hh >= Hn) continue;
            const float* row = sP + hh * Wn;
            float4 a = *(const float4*)(row + w4);
            float xm = (w4 > 0)  ? row[w4 - 1] : 0.f;
            float xq = (w4 < 60) ? row[w4 + 4] : 0.f;
            float k0 = wk[(dh + 1) * 3], k1 = wk[(dh + 1) * 3 + 1], k2 = wk[(dh + 1) * 3 + 2];
            o0 += k0 * xm  + k1 * a.x + k2 * a.y;
            o1 += k0 * a.x + k1 * a.y + k2 * a.z;
            o2 += k0 * a.y + k1 * a.z + k2 * a.w;
            o3 += k0 * a.z + k1 * a.w + k2 * xq;
        }
        sx += o0 + o1 + o2 + o3;
        ushort4 pk = { f2b(o0), f2b(o1), f2b(o2), f2b(o3) };
        *(ushort4*)(Fx + grp * 4) = pk;
    }
#pragma unroll
    for (int off = 32; off; off >>= 1) {
        sx += __shfl_down(sx, off);
        sy += __shfl_down(sy, off);
    }
    int lane = t & 63, wv = t >> 6;
    if (lane == 0) { red[wv][0] = sx; red[wv][1] = sy; }
    __syncthreads();
    if (t < 2)
        pws[bc * 2 + t] = (red[0][t] + red[1][t] + red[2][t] + red[3][t]) * (1.f / HWn);
}

// ---------------------------------------------------------------------------
// K2: 32 blocks (4 per batch). means -> MLP -> cf quarter; converts wf (ws)
// and ws (out-scratch) slices to bf16.
// ---------------------------------------------------------------------------
__global__ __launch_bounds__(256) void k_ctx(
    const float* __restrict__ pws,
    const float* __restrict__ w1, const float* __restrict__ w2,
    const float* __restrict__ w3, const float* __restrict__ wf,
    const float* __restrict__ wsp, float* __restrict__ cf,
    unsigned short* __restrict__ wfb, unsigned short* __restrict__ wsb)
{
    int blk = blockIdx.x, b = blk >> 2, qd = blk & 3;
    int t = threadIdx.x;
    for (int i = t; i < 1024; i += 256) {
        int j = blk * 1024 + i;
        wfb[j] = f2b(wf[j]);
    }
    if (t < 128) {
        int j = blk * 128 + t;
        int tt = j >> 8, c = j & 255;
        wsb[j] = (tt < KK) ? f2b(wsp[tt * 256 + c]) : (unsigned short)0;
    }
    __shared__ float mfc[256], c1[64], c2[64];
    mfc[t] = (t < 128) ? pws[(b * Cn + t) * 2]
                       : pws[(b * Cn + (t - 128)) * 2 + 1];
    __syncthreads();
    if (t < 64) {
        const float4* wr = (const float4*)(w1 + t * 256);
        float a = 0.f;
        for (int c = 0; c < 64; c++) {
            float4 v = wr[c];
            a += v.x * mfc[c*4] + v.y * mfc[c*4+1] + v.z * mfc[c*4+2] + v.w * mfc[c*4+3];
        }
        c1[t] = a;
    }
    __syncthreads();
    if (t < 64) {
        const float4* wr = (const float4*)(w2 + t * 64);
        float a = 0.f;
        for (int c = 0; c < 16; c++) {
            float4 v = wr[c];
            a += v.x * c1[c*4] + v.y * c1[c*4+1] + v.z * c1[c*4+2] + v.w * c1[c*4+3];
        }
        c2[t] = fmaxf(a, 0.f);
    }
    __syncthreads();
    for (int j = qd * 288 + t; j < qd * 288 + 288; j += 256) {
        const float4* wr = (const float4*)(w3 + j * 64);
        float a = 0.f;
        for (int c = 0; c < 16; c++) {
            float4 v = wr[c];
            a += v.x * c2[c*4] + v.y * c2[c*4+1] + v.z * c2[c*4+2] + v.w * c2[c*4+3];
        }
        cf[b * Cn * KK + j] = a;
    }
}

// ---------------------------------------------------------------------------
// K3: PURE GEMM: sf[16][px] = wsb[16][256] @ [Xs;Y2][256][px], 64-px chunks.
// B staged from global (Xs bf16 + Y2 f32) into swizzled LDS. sfB bf16 out.
// ---------------------------------------------------------------------------
__global__ __launch_bounds__(256, 4) void k_sf(
    const unsigned short* __restrict__ F, const float* __restrict__ Y2,
    const unsigned short* __restrict__ wsb, unsigned short* __restrict__ sfB)
{
    __shared__ unsigned short sFt[Wn][256];   // 32 KB

    int bid = blockIdx.x;
    int b = bid & 7, chnk = bid >> 3;
    int px0 = chnk * 64;
    int t = threadIdx.x, pq = t & 15, c0 = t >> 4;

#pragma unroll
    for (int i = 0; i < 8; i++) {
        int c = c0 + 16 * i;
        ushort4 xv = *(const ushort4*)(F + ((size_t)(b * 256 + c) * HWn + px0 + pq * 4));
        const unsigned short* xa = (const unsigned short*)&xv;
        float4 yv = *(const float4*)(Y2 + ((size_t)(b * Cn + c) * HWn + px0 + pq * 4));
        float ya[4] = { yv.x, yv.y, yv.z, yv.w };
#pragma unroll
        for (int j = 0; j < 4; j++) {
            int px = pq * 4 + j;
            sFt[px][c ^ SWZ(px)] = xa[j];
            sFt[px][(128 + c) ^ SWZ(px)] = f2b(ya[j]);
        }
    }
    __syncthreads();

    int lane = t & 63, wv = t >> 6;
    int l16 = lane & 15, half = lane >> 4, kk = half * 8;
    int px = wv * 16 + l16;
    f32x4 acc = (f32x4){0.f, 0.f, 0.f, 0.f};
#pragma unroll
    for (int ks = 0; ks < 8; ks++) {
        short8 av = *(const short8*)(wsb + l16 * 256 + ks * 32 + kk);
        int col = (ks * 32 + kk) ^ SWZ(px);
        short8 bv = *(const short8*)(&sFt[px][0] + col);
        acc = __builtin_amdgcn_mfma_f32_16x16x32_bf16(av, bv, acc, 0, 0, 0);
    }
#pragma unroll
    for (int r = 0; r < 4; r++) {
        int tt = half * 4 + r;
        if (tt < KK)
            sfB[(size_t)(b * KK + tt) * HWn + px0 + px] = f2b(acc[r]);
    }
}

// ---------------------------------------------------------------------------
// K4: PURE STREAMING dynamic conv. Block = (b, 4-ch group, 16-row group).
// X2 rows (with halo) staged in LDS f32; vectorized shifted-row taps; writes
// dyn bf16 into F[b][128+c][px].
// ---------------------------------------------------------------------------
__global__ __launch_bounds__(256, 4) void k_dyn(
    const float* __restrict__ X2, const float* __restrict__ cf,
    const unsigned short* __restrict__ sfB, unsigned short* __restrict__ F)
{
    __shared__ float sX[4][18][Wn];   // 18.4 KB

    int bid = blockIdx.x;
    int b = bid & 7, rest = bid >> 3;
    int cq = rest & 31, hq = rest >> 5;
    int cbase = cq * 4, h0 = hq * 16;
    int t = threadIdx.x;

    for (int idx = t; idx < 1152; idx += 256) {
        int ch = idx / 288, rem = idx - ch * 288;
        int rr = rem >> 4, q4 = rem & 15;
        int g = h0 - 1 + rr;
        float4 v = (g >= 0 && g < Hn)
            ? *(const float4*)(X2 + ((size_t)(b * Cn + cbase + ch) * HWn + g * Wn + q4 * 4))
            : (float4){0.f, 0.f, 0.f, 0.f};
        *(float4*)&sX[ch][rr][q4 * 4] = v;
    }
    __syncthreads();

    int ch = t >> 6, r = (t >> 2) & 15, wq = t & 3;
    int c = cbase + ch, h = h0 + r, w0 = wq * 16;

    float cfr[9];
#pragma unroll
    for (int q = 0; q < 9; q++) cfr[q] = cf[(b * Cn + c) * 9 + q];

    unsigned int pk[8];
#pragma unroll
    for (int sub = 0; sub < 4; sub++) {
        int w4 = w0 + sub * 4;
        float sfv[9][4];
#pragma unroll
        for (int q = 0; q < 9; q++) {
            ushort4 s = *(const ushort4*)(sfB + (size_t)(b * KK + q) * HWn + h * Wn + w4);
            sfv[q][0] = b2f(s.x); sfv[q][1] = b2f(s.y);
            sfv[q][2] = b2f(s.z); sfv[q][3] = b2f(s.w);
        }
        float o0 = 0.f, o1 = 0.f, o2 = 0.f, o3 = 0.f;
#pragma unroll
        for (int dh = -1; dh <= 1; dh++) {
            const float* row = &sX[ch][r + 1 + dh][0];
            float4 a = *(const float4*)(row + w4);
            float xm = (w4 > 0)  ? row[w4 - 1] : 0.f;
            float xq = (w4 < 60) ? row[w4 + 4] : 0.f;
            int tb = (dh + 1) * 3;
            float kl0 = cfr[tb], kc0 = cfr[tb + 1], kr0 = cfr[tb + 2];
            o0 += xm  * (kl0 + sfv[tb][0]) + a.x * (kc0 + sfv[tb+1][0]) + a.y * (kr0 + sfv[tb+2][0]);
            o1 += a.x * (kl0 + sfv[tb][1]) + a.y * (kc0 + sfv[tb+1][1]) + a.z * (kr0 + sfv[tb+2][1]);
            o2 += a.y * (kl0 + sfv[tb][2]) + a.z * (kc0 + sfv[tb+1][2]) + a.w * (kr0 + sfv[tb+2][2]);
            o3 += a.z * (kl0 + sfv[tb][3]) + a.w * (kc0 + sfv[tb+1][3]) + xq  * (kr0 + sfv[tb+2][3]);
        }
        pk[sub * 2]     = ((unsigned int)f2b(o1) << 16) | f2b(o0);
        pk[sub * 2 + 1] = ((unsigned int)f2b(o3) << 16) | f2b(o2);
    }
    unsigned short* dst = F + (size_t)(b * 256 + 128 + c) * HWn + h * Wn + w0;
    *(uint4*)(dst)     = *(uint4*)(pk);
    *(uint4*)(dst + 8) = *(uint4*)(pk + 4);
}

// ---------------------------------------------------------------------------
// K5: PURE GEMM: out[128][px] = wfb[128][256] @ F[256][px], 64-px chunks.
// ---------------------------------------------------------------------------
__global__ __launch_bounds__(512, 2) void k_gemm(
    const unsigned short* __restrict__ F, const unsigned short* __restrict__ wfb,
    float* __restrict__ out)
{
    __shared__ unsigned short sFt[Wn][256];   // 32 KB

    int bid = blockIdx.x;
    int b = bid & 7, chnk = bid >> 3;
    int px0 = chnk * 64;
    int t = threadIdx.x, pq = t & 15, c0 = t >> 4;   // c0 in [0,32)

#pragma unroll
    for (int i = 0; i < 8; i++) {
        int c = c0 + 32 * i;
        ushort4 v = *(const ushort4*)(F + ((size_t)(b * 256 + c) * HWn + px0 + pq * 4));
        const unsigned short* va = (const unsigned short*)&v;
#pragma unroll
        for (int j = 0; j < 4; j++) {
            int px = pq * 4 + j;
            sFt[px][c ^ SWZ(px)] = va[j];
        }
    }
    __syncthreads();

    int lane = t & 63, wv = t >> 6;
    int l16 = lane & 15, half = lane >> 4, kk = half * 8;
    int o0 = (wv & 3) * 32, pxh = (wv >> 2) * 32;

    f32x4 acc[2][2];
#pragma unroll
    for (int m = 0; m < 2; m++)
#pragma unroll
        for (int n = 0; n < 2; n++)
            acc[m][n] = (f32x4){0.f, 0.f, 0.f, 0.f};

#pragma unroll
    for (int ks = 0; ks < 8; ks++) {
        short8 av[2];
#pragma unroll
        for (int m = 0; m < 2; m++)
            av[m] = *(const short8*)(wfb + (o0 + m * 16 + l16) * 256 + ks * 32 + kk);
#pragma unroll
        for (int n = 0; n < 2; n++) {
            int px = pxh + n * 16 + l16;
            int col = (ks * 32 + kk) ^ SWZ(px);
            short8 bv = *(const short8*)(&sFt[px][0] + col);
#pragma unroll
            for (int m = 0; m < 2; m++)
                acc[m][n] = __builtin_amdgcn_mfma_f32_16x16x32_bf16(av[m], bv, acc[m][n], 0, 0, 0);
        }
    }
#pragma unroll
    for (int m = 0; m < 2; m++)
#pragma unroll
        for (int n = 0; n < 2; n++)
#pragma unroll
            for (int r = 0; r < 4; r++) {
                int o = o0 + m * 16 + half * 4 + r;
                int px = pxh + n * 16 + l16;
                __builtin_nontemporal_store(
                    acc[m][n][r], &out[(size_t)(b * Cn + o) * HWn + px0 + px]);
            }
}

// ---------------------------------------------------------------------------
extern "C" void kernel_launch(void* const* d_in, const int* in_sizes, int n_in,
                              void* d_out, int out_size, void* d_ws, size_t ws_size,
                              hipStream_t stream) {
    (void)in_sizes; (void)n_in; (void)out_size; (void)ws_size;
    const float* X2  = (const float*)d_in[0];
    const float* Y2  = (const float*)d_in[1];
    const float* sw  = (const float*)d_in[2];
    const float* w1  = (const float*)d_in[3];
    const float* w2  = (const float*)d_in[4];
    const float* w3  = (const float*)d_in[5];
    const float* wsp = (const float*)d_in[6];
    const float* wf  = (const float*)d_in[7];
    float* out = (float*)d_out;

    // ws layout (floats). Total = 4,221,952 f = 16,887,808 B (== verified floor).
    float* wsf = (float*)d_ws;
    unsigned short* F = (unsigned short*)wsf;              // 8*256*4096 u16 (16 MB)
    float* pws = wsf + 2097152;                            // 2048 f
    float* cf  = wsf + 2099200;                            // 9216 f
    unsigned short* wfb = (unsigned short*)(wsf + 2108416); // 32768 u16
    // + wfb occupies 16384 f -> ends at 2124800 f... (F is 2*2097152 f)
    // recompute: F = 4194304 f? No: 8*256*4096 u16 = 8388608 u16 = 4194304 f.
    // Fix offsets:
    pws = wsf + 4194304;                                   // 2048 f
    cf  = wsf + 4196352;                                   // 9216 f
    wfb = (unsigned short*)(wsf + 4205568);                // 32768 u16 = 16384 f -> end 4221952 f

    // d_out scratch (overwritten by k_gemm before validation):
    unsigned short* outScratch = (unsigned short*)d_out;
    unsigned short* sfB = outScratch;                      // 8*9*4096 u16 (576 KB)
    unsigned short* wsb = outScratch + 294912;             // 4096 u16

    hipLaunchKernelGGL(k_pre, dim3(Bn * Cn), dim3(256), 0, stream,
                       X2, Y2, sw, F, pws);
    hipLaunchKernelGGL(k_ctx, dim3(32), dim3(256), 0, stream,
                       pws, w1, w2, w3, wf, wsp, cf, wfb, wsb);
    hipLaunchKernelGGL(k_sf, dim3(Bn * 64), dim3(256), 0, stream,
                       F, Y2, wsb, sfB);
    hipLaunchKernelGGL(k_dyn, dim3(Bn * 128), dim3(256), 0, stream,
                       X2, cf, sfB, F);
    hipLaunchKernelGGL(k_gemm, dim3(Bn * 64), dim3(512), 0, stream,
                       F, wfb, out);
}

// Round 10
// 76.002 us; speedup vs baseline: 1.0144x; 1.0144x over previous
//
#include <hip/hip_runtime.h>
#include <hip/hip_bf16.h>

#define Bn 8
#define Cn 128
#define Hn 64
#define Wn 64
#define HWn 4096
#define KK 9

typedef short short8 __attribute__((ext_vector_type(8)));
typedef float f32x4 __attribute__((ext_vector_type(4)));

#define SWZ(px) ((((px) >> 1) & 7) << 3)

__device__ inline unsigned short f2b(float v) {
    __hip_bfloat16 h = __float2bfloat16(v);
    return *reinterpret_cast<unsigned short*>(&h);
}
__device__ inline float b2f(unsigned short u) {
    return __uint_as_float(((unsigned int)u) << 16);
}

// ---------------------------------------------------------------------------
// K1: per-(b,c) plane streaming sums (stride 10):
//  [0]=sum(X2) [1]=row0 [2]=row63 [3]=col0 [4]=col63 [5]=sum(Y2)
//  [6]=x00 [7]=x063 [8]=x630 [9]=x6363
// ---------------------------------------------------------------------------
__global__ __launch_bounds__(256) void k_pre(
    const float* __restrict__ X2, const float* __restrict__ Y2,
    float* __restrict__ pws)
{
    int bc = blockIdx.x, t = threadIdx.x;
    const float4* xp = (const float4*)(X2 + (size_t)bc * HWn);
    const float4* yp = (const float4*)(Y2 + (size_t)bc * HWn);
    float v[10];
#pragma unroll
    for (int k = 0; k < 10; k++) v[k] = 0.f;
#pragma unroll
    for (int i = 0; i < 4; i++) {
        int q = t + i * 256;
        float4 x = xp[q], y = yp[q];
        float s4 = x.x + x.y + x.z + x.w;
        v[0] += s4;
        v[5] += y.x + y.y + y.z + y.w;
        int px = q * 4, h = px >> 6, w4 = px & 63;
        if (h == 0)   v[1] += s4;
        if (h == 63)  v[2] += s4;
        if (w4 == 0)  v[3] += x.x;
        if (w4 == 60) v[4] += x.w;
        if (px == 0)    v[6] += x.x;
        if (px == 60)   v[7] += x.w;
        if (px == 4032) v[8] += x.x;
        if (px == 4092) v[9] += x.w;
    }
#pragma unroll
    for (int k = 0; k < 10; k++)
#pragma unroll
        for (int off = 32; off; off >>= 1)
            v[k] += __shfl_down(v[k], off);
    __shared__ float red[4][10];
    int lane = t & 63, wv = t >> 6;
    if (lane == 0) {
#pragma unroll
        for (int k = 0; k < 10; k++) red[wv][k] = v[k];
    }
    __syncthreads();
    if (t < 10) pws[bc * 10 + t] = red[0][t] + red[1][t] + red[2][t] + red[3][t];
}

// ---------------------------------------------------------------------------
// K2: 32 blocks (4 per batch). Closed-form mean(Xs), mean(Y2) -> MLP -> cf
// quarter. Also converts wf/ws slices to bf16.
// ---------------------------------------------------------------------------
__global__ __launch_bounds__(256) void k_ctx(
    const float* __restrict__ pws, const float* __restrict__ sw,
    const float* __restrict__ w1, const float* __restrict__ w2,
    const float* __restrict__ w3, const float* __restrict__ wf,
    const float* __restrict__ wsp, float* __restrict__ cf,
    unsigned short* __restrict__ wfb, unsigned short* __restrict__ wsb)
{
    int blk = blockIdx.x, b = blk >> 2, qd = blk & 3;
    int t = threadIdx.x;
    for (int i = t; i < 1024; i += 256) {
        int j = blk * 1024 + i;
        wfb[j] = f2b(wf[j]);
    }
    if (t < 128) {
        int j = blk * 128 + t;
        int tt = j >> 8, c = j & 255;
        wsb[j] = (tt < KK) ? f2b(wsp[tt * 256 + c]) : (unsigned short)0;
    }
    __shared__ float mfc[256], c1[64], c2[64];
    if (t < 128) {
        const float* S = pws + (b * Cn + t) * 10;
        float T = S[0];
        float R[3]  = { S[2], 0.f, S[1] };
        float Cc[3] = { S[4], 0.f, S[3] };
        float Xc[3][3] = {{S[9], 0.f, S[8]}, {0.f, 0.f, 0.f}, {S[7], 0.f, S[6]}};
        float a = 0.f;
#pragma unroll
        for (int i = 0; i < 3; i++)
#pragma unroll
            for (int j = 0; j < 3; j++)
                a += sw[t * 9 + i * 3 + j] * (T - R[i] - Cc[j] + Xc[i][j]);
        mfc[t] = a * (1.f / HWn);
    } else {
        mfc[t] = pws[(b * Cn + (t - 128)) * 10 + 5] * (1.f / HWn);
    }
    __syncthreads();
    if (t < 64) {
        const float4* wr = (const float4*)(w1 + t * 256);
        float a = 0.f;
        for (int c = 0; c < 64; c++) {
            float4 v = wr[c];
            a += v.x * mfc[c*4] + v.y * mfc[c*4+1] + v.z * mfc[c*4+2] + v.w * mfc[c*4+3];
        }
        c1[t] = a;
    }
    __syncthreads();
    if (t < 64) {
        const float4* wr = (const float4*)(w2 + t * 64);
        float a = 0.f;
        for (int c = 0; c < 16; c++) {
            float4 v = wr[c];
            a += v.x * c1[c*4] + v.y * c1[c*4+1] + v.z * c1[c*4+2] + v.w * c1[c*4+3];
        }
        c2[t] = fmaxf(a, 0.f);
    }
    __syncthreads();
    for (int j = qd * 288 + t; j < qd * 288 + 288; j += 256) {
        const float4* wr = (const float4*)(w3 + j * 64);
        float a = 0.f;
        for (int c = 0; c < 16; c++) {
            float4 v = wr[c];
            a += v.x * c2[c*4] + v.y * c2[c*4+1] + v.z * c2[c*4+2] + v.w * c2[c*4+3];
        }
        cf[b * Cn * KK + j] = a;
    }
}

// ---------------------------------------------------------------------------
// K3: dual depthwise conv. Block = (b,c): stage X2 plane in LDS, compute
// Xs = conv(X2, sw[c]) and V = conv(X2, cf[b,c]) vectorized; write bf16 to
// XV rows c (Xs) and 128+c (V).
// ---------------------------------------------------------------------------
__global__ __launch_bounds__(256) void k_conv(
    const float* __restrict__ X2, const float* __restrict__ sw,
    const float* __restrict__ cf, unsigned short* __restrict__ XV)
{
    __shared__ float sP[HWn];
    int bc = blockIdx.x, b = bc >> 7, c = bc & 127, t = threadIdx.x;
    const float4* xp = (const float4*)(X2 + (size_t)bc * HWn);
#pragma unroll
    for (int i = 0; i < 4; i++) {
        int q = t + i * 256;
        ((float4*)sP)[q] = xp[q];
    }
    __syncthreads();

    float wk[9], vk[9];
#pragma unroll
    for (int i = 0; i < 9; i++) {
        wk[i] = sw[c * 9 + i];
        vk[i] = cf[(b * Cn + c) * 9 + i];
    }
    unsigned short* Xs = XV + (size_t)(b * 256 + c) * HWn;
    unsigned short* Vd = XV + (size_t)(b * 256 + 128 + c) * HWn;
#pragma unroll
    for (int g = 0; g < 4; g++) {
        int grp = t + g * 256;
        int h = grp >> 4, w4 = (grp & 15) * 4;
        float o0 = 0.f, o1 = 0.f, o2 = 0.f, o3 = 0.f;
        float p0 = 0.f, p1 = 0.f, p2 = 0.f, p3 = 0.f;
#pragma unroll
        for (int dh = -1; dh <= 1; dh++) {
            int hh = h + dh;
            if (hh < 0 || hh >= Hn) continue;
            const float* row = sP + hh * Wn;
            float4 a = *(const float4*)(row + w4);
            float xm = (w4 > 0)  ? row[w4 - 1] : 0.f;
            float xq = (w4 < 60) ? row[w4 + 4] : 0.f;
            int tb = (dh + 1) * 3;
            float k0 = wk[tb], k1 = wk[tb + 1], k2 = wk[tb + 2];
            float m0 = vk[tb], m1 = vk[tb + 1], m2 = vk[tb + 2];
            o0 += k0 * xm  + k1 * a.x + k2 * a.y;
            o1 += k0 * a.x + k1 * a.y + k2 * a.z;
            o2 += k0 * a.y + k1 * a.z + k2 * a.w;
            o3 += k0 * a.z + k1 * a.w + k2 * xq;
            p0 += m0 * xm  + m1 * a.x + m2 * a.y;
            p1 += m0 * a.x + m1 * a.y + m2 * a.z;
            p2 += m0 * a.y + m1 * a.z + m2 * a.w;
            p3 += m0 * a.z + m1 * a.w + m2 * xq;
        }
        ushort4 pk1 = { f2b(o0), f2b(o1), f2b(o2), f2b(o3) };
        *(ushort4*)(Xs + grp * 4) = pk1;
        ushort4 pk2 = { f2b(p0), f2b(p1), f2b(p2), f2b(p3) };
        *(ushort4*)(Vd + grp * 4) = pk2;
    }
}

// ---------------------------------------------------------------------------
// K4: PURE GEMM, K=128: U[o][px] = wf_d[o][:] @ X2[b][:][px], bf16 out.
// wf_d = wfb columns 128..255.
// ---------------------------------------------------------------------------
__global__ __launch_bounds__(512, 2) void k_gemmU(
    const float* __restrict__ X2, const unsigned short* __restrict__ wfb,
    unsigned short* __restrict__ U)
{
    __shared__ unsigned short sB[Wn][128];   // 16 KB

    int bid = blockIdx.x;
    int b = bid & 7, chnk = bid >> 3;
    int px0 = chnk * 64;
    int t = threadIdx.x, pq = t & 15, c0 = t >> 4;   // c0 in [0,32)

#pragma unroll
    for (int i = 0; i < 4; i++) {
        int c = c0 + 32 * i;
        float4 v = *(const float4*)(X2 + ((size_t)(b * Cn + c) * HWn + px0 + pq * 4));
        float va[4] = { v.x, v.y, v.z, v.w };
#pragma unroll
        for (int j = 0; j < 4; j++) {
            int px = pq * 4 + j;
            sB[px][c ^ SWZ(px)] = f2b(va[j]);
        }
    }
    __syncthreads();

    int lane = t & 63, wv = t >> 6;
    int l16 = lane & 15, half = lane >> 4, kk = half * 8;
    int o0 = (wv & 3) * 32, pxh = (wv >> 2) * 32;

    f32x4 acc[2][2];
#pragma unroll
    for (int m = 0; m < 2; m++)
#pragma unroll
        for (int n = 0; n < 2; n++)
            acc[m][n] = (f32x4){0.f, 0.f, 0.f, 0.f};

#pragma unroll
    for (int ks = 0; ks < 4; ks++) {
        short8 av[2];
#pragma unroll
        for (int m = 0; m < 2; m++)
            av[m] = *(const short8*)(wfb + (o0 + m * 16 + l16) * 256 + 128 + ks * 32 + kk);
#pragma unroll
        for (int n = 0; n < 2; n++) {
            int px = pxh + n * 16 + l16;
            int col = (ks * 32 + kk) ^ SWZ(px);
            short8 bv = *(const short8*)(&sB[px][0] + col);
#pragma unroll
            for (int m = 0; m < 2; m++)
                acc[m][n] = __builtin_amdgcn_mfma_f32_16x16x32_bf16(av[m], bv, acc[m][n], 0, 0, 0);
        }
    }
#pragma unroll
    for (int m = 0; m < 2; m++)
#pragma unroll
        for (int n = 0; n < 2; n++)
#pragma unroll
            for (int r = 0; r < 4; r++) {
                int o = o0 + m * 16 + half * 4 + r;
                int px = pxh + n * 16 + l16;
                U[(size_t)(b * Cn + o) * HWn + px0 + px] = f2b(acc[m][n][r]);
            }
}

// ---------------------------------------------------------------------------
// K5: PURE GEMM: sf[16][px] = wsb[16][256] @ [Xs;Y2][256][px]. f32 out.
// ---------------------------------------------------------------------------
__global__ __launch_bounds__(256, 4) void k_sf(
    const unsigned short* __restrict__ XV, const float* __restrict__ Y2,
    const unsigned short* __restrict__ wsb, float* __restrict__ sfB)
{
    __shared__ unsigned short sFt[Wn][256];   // 32 KB

    int bid = blockIdx.x;
    int b = bid & 7, chnk = bid >> 3;
    int px0 = chnk * 64;
    int t = threadIdx.x, pq = t & 15, c0 = t >> 4;

#pragma unroll
    for (int i = 0; i < 8; i++) {
        int c = c0 + 16 * i;
        ushort4 xv = *(const ushort4*)(XV + ((size_t)(b * 256 + c) * HWn + px0 + pq * 4));
        const unsigned short* xa = (const unsigned short*)&xv;
        float4 yv = *(const float4*)(Y2 + ((size_t)(b * Cn + c) * HWn + px0 + pq * 4));
        float ya[4] = { yv.x, yv.y, yv.z, yv.w };
#pragma unroll
        for (int j = 0; j < 4; j++) {
            int px = pq * 4 + j;
            sFt[px][c ^ SWZ(px)] = xa[j];
            sFt[px][(128 + c) ^ SWZ(px)] = f2b(ya[j]);
        }
    }
    __syncthreads();

    int lane = t & 63, wv = t >> 6;
    int l16 = lane & 15, half = lane >> 4, kk = half * 8;
    int px = wv * 16 + l16;
    f32x4 acc = (f32x4){0.f, 0.f, 0.f, 0.f};
#pragma unroll
    for (int ks = 0; ks < 8; ks++) {
        short8 av = *(const short8*)(wsb + l16 * 256 + ks * 32 + kk);
        int col = (ks * 32 + kk) ^ SWZ(px);
        short8 bv = *(const short8*)(&sFt[px][0] + col);
        acc = __builtin_amdgcn_mfma_f32_16x16x32_bf16(av, bv, acc, 0, 0, 0);
    }
#pragma unroll
    for (int r = 0; r < 4; r++) {
        int tt = half * 4 + r;
        if (tt < KK)
            sfB[(size_t)(b * KK + tt) * HWn + px0 + px] = acc[r];
    }
}

// ---------------------------------------------------------------------------
// K6: PURE GEMM: W1[o][px] = wfb[128][256] @ XV[256][px], bf16 out.
// ---------------------------------------------------------------------------
__global__ __launch_bounds__(512, 2) void k_gemmW1(
    const unsigned short* __restrict__ XV, const unsigned short* __restrict__ wfb,
    unsigned short* __restrict__ W1)
{
    __shared__ unsigned short sFt[Wn][256];   // 32 KB

    int bid = blockIdx.x;
    int b = bid & 7, chnk = bid >> 3;
    int px0 = chnk * 64;
    int t = threadIdx.x, pq = t & 15, c0 = t >> 4;   // c0 in [0,32)

#pragma unroll
    for (int i = 0; i < 8; i++) {
        int c = c0 + 32 * i;
        ushort4 v = *(const ushort4*)(XV + ((size_t)(b * 256 + c) * HWn + px0 + pq * 4));
        const unsigned short* va = (const unsigned short*)&v;
#pragma unroll
        for (int j = 0; j < 4; j++) {
            int px = pq * 4 + j;
            sFt[px][c ^ SWZ(px)] = va[j];
        }
    }
    __syncthreads();

    int lane = t & 63, wv = t >> 6;
    int l16 = lane & 15, half = lane >> 4, kk = half * 8;
    int o0 = (wv & 3) * 32, pxh = (wv >> 2) * 32;

    f32x4 acc[2][2];
#pragma unroll
    for (int m = 0; m < 2; m++)
#pragma unroll
        for (int n = 0; n < 2; n++)
            acc[m][n] = (f32x4){0.f, 0.f, 0.f, 0.f};

#pragma unroll
    for (int ks = 0; ks < 8; ks++) {
        short8 av[2];
#pragma unroll
        for (int m = 0; m < 2; m++)
            av[m] = *(const short8*)(wfb + (o0 + m * 16 + l16) * 256 + ks * 32 + kk);
#pragma unroll
        for (int n = 0; n < 2; n++) {
            int px = pxh + n * 16 + l16;
            int col = (ks * 32 + kk) ^ SWZ(px);
            short8 bv = *(const short8*)(&sFt[px][0] + col);
#pragma unroll
            for (int m = 0; m < 2; m++)
                acc[m][n] = __builtin_amdgcn_mfma_f32_16x16x32_bf16(av[m], bv, acc[m][n], 0, 0, 0);
        }
    }
#pragma unroll
    for (int m = 0; m < 2; m++)
#pragma unroll
        for (int n = 0; n < 2; n++)
#pragma unroll
            for (int r = 0; r < 4; r++) {
                int o = o0 + m * 16 + half * 4 + r;
                int px = pxh + n * 16 + l16;
                W1[(size_t)(b * Cn + o) * HWn + px0 + px] = f2b(acc[m][n][r]);
            }
}

// ---------------------------------------------------------------------------
// K7: streaming finish. Block = (b,h), 512 threads (w = t&63, 16 o's each).
// out[o][w] = W1[o][w] + sum_t sf[t][w] * Upad[o][h+dh][w+dw].
// No LDS, no barriers; shuffles give w+-1; hm/hp guards give h+-1 zeros.
// ---------------------------------------------------------------------------
__global__ __launch_bounds__(512) void k_fin(
    const unsigned short* __restrict__ U, const unsigned short* __restrict__ W1,
    const float* __restrict__ sfB, float* __restrict__ out)
{
    int bid = blockIdx.x;
    int b = bid & 7, h = bid >> 3;
    int t = threadIdx.x;
    int w = t & 63, og = t >> 6;        // og in [0,8): o = og*16 + i
    bool hm = h > 0, hp = h < Hn - 1;

    float sfw[9];
#pragma unroll
    for (int q = 0; q < 9; q++)
        sfw[q] = sfB[(size_t)(b * KK + q) * HWn + h * Wn + w];

    size_t base = (size_t)(b * Cn + og * 16) * HWn + h * Wn + w;
#pragma unroll
    for (int i = 0; i < 16; i++) {
        const unsigned short* up = U + base + (size_t)i * HWn;
        float r0 = hm ? b2f(up[-Wn]) : 0.f;
        float r1 = b2f(up[0]);
        float r2 = hp ? b2f(up[Wn]) : 0.f;
        float xl0 = __shfl_up(r0, 1), xr0 = __shfl_down(r0, 1);
        float xl1 = __shfl_up(r1, 1), xr1 = __shfl_down(r1, 1);
        float xl2 = __shfl_up(r2, 1), xr2 = __shfl_down(r2, 1);
        if (w == 0)  { xl0 = 0.f; xl1 = 0.f; xl2 = 0.f; }
        if (w == 63) { xr0 = 0.f; xr1 = 0.f; xr2 = 0.f; }
        float a = sfw[0] * xl0 + sfw[1] * r0 + sfw[2] * xr0
                + sfw[3] * xl1 + sfw[4] * r1 + sfw[5] * xr1
                + sfw[6] * xl2 + sfw[7] * r2 + sfw[8] * xr2;
        a += b2f(W1[base + (size_t)i * HWn]);
        __builtin_nontemporal_store(a, &out[base + (size_t)i * HWn]);
    }
}

// ---------------------------------------------------------------------------
extern "C" void kernel_launch(void* const* d_in, const int* in_sizes, int n_in,
                              void* d_out, int out_size, void* d_ws, size_t ws_size,
                              hipStream_t stream) {
    (void)in_sizes; (void)n_in; (void)out_size; (void)ws_size;
    const float* X2  = (const float*)d_in[0];
    const float* Y2  = (const float*)d_in[1];
    const float* sw  = (const float*)d_in[2];
    const float* w1  = (const float*)d_in[3];
    const float* w2  = (const float*)d_in[4];
    const float* w3  = (const float*)d_in[5];
    const float* wsp = (const float*)d_in[6];
    const float* wf  = (const float*)d_in[7];
    float* out = (float*)d_out;

    // ws layout (float offsets); total ~35 MB (ws is ~268 MB per fill evidence).
    float* wsf = (float*)d_ws;
    unsigned short* XV = (unsigned short*)wsf;             // 8*256*4096 u16 (16 MB)
    unsigned short* U  = (unsigned short*)(wsf + 4194304); // 8*128*4096 u16 (8 MB)
    unsigned short* W1 = (unsigned short*)(wsf + 6291456); // 8*128*4096 u16 (8 MB)
    float* sfB = wsf + 8388608;                            // 8*9*4096 f (1.18 MB)
    float* pws = wsf + 8683520;                            // 10240 f
    float* cf  = wsf + 8693760;                            // 9216 f
    unsigned short* wfb = (unsigned short*)(wsf + 8702976); // 32768 u16
    unsigned short* wsb = (unsigned short*)(wsf + 8719360); // 4096 u16

    hipLaunchKernelGGL(k_pre, dim3(Bn * Cn), dim3(256), 0, stream, X2, Y2, pws);
    hipLaunchKernelGGL(k_ctx, dim3(32), dim3(256), 0, stream,
                       pws, sw, w1, w2, w3, wf, wsp, cf, wfb, wsb);
    hipLaunchKernelGGL(k_gemmU, dim3(Bn * 64), dim3(512), 0, stream,
                       X2, wfb, U);
    hipLaunchKernelGGL(k_conv, dim3(Bn * Cn), dim3(256), 0, stream,
                       X2, sw, cf, XV);
    hipLaunchKernelGGL(k_sf, dim3(Bn * 64), dim3(256), 0, stream,
                       XV, Y2, wsb, sfB);
    hipLaunchKernelGGL(k_gemmW1, dim3(Bn * 64), dim3(512), 0, stream,
                       XV, wfb, W1);
    hipLaunchKernelGGL(k_fin, dim3(Bn * Hn), dim3(512), 0, stream,
                       U, W1, sfB, out);
}